// Round 2
// baseline (624.291 us; speedup 1.0000x reference)
//
#include <hip/hip_runtime.h>

// AttDownsample: x [32,768,56,56] f32 -> y [32,768,28,28] f32
// v2 (resubmit; prior run died to container infra failure, not kernel):
// (1) scores = chunked channel-loop blocks w/ register accumulation (1792 blocks,
//     0.9M atomics vs 10.8M, 1.25x row refetch), (2) softmax LDS-staged coalesced IO,
//     (3) merge stages per-n attn slice in LDS (kills 173M scalar global gathers).
// ws layout: scores/attn [N,Ho,Wo,9] f32 = 903168 B.

constexpr int N_  = 32;
constexpr int C_  = 768;
constexpr int H_  = 56;
constexpr int W_  = 56;
constexpr int HO_ = 28;
constexpr int WO_ = 28;
constexpr int NPIX = N_ * HO_ * WO_;          // 25088

// ---- kernel 1: scores ----
constexpr int K1_CHUNKS = 4;                   // channel chunks (atomic contenders)
constexpr int K1_CCH    = C_ / K1_CHUNKS;      // 192 channels per block
constexpr int K1_SC     = 16;                  // channels per LDS sub-chunk
constexpr int K1_NSUB   = K1_CCH / K1_SC;      // 12
constexpr int K1_TW     = 58;                  // ghost col 0, data 1..56, ghost 57
constexpr int K1_TR     = 5;                   // 5 input rows cover 2 output rows

__global__ __launch_bounds__(256)
void scores_kernel(const float* __restrict__ x, float* __restrict__ scores) {
    __shared__ float tile[K1_SC * K1_TR * K1_TW];   // 18560 B
    __shared__ float sred[4 * 56 * 9];              // 8064 B

    const int tid   = threadIdx.x;
    const int blk   = blockIdx.x;
    const int chunk = blk / (N_ * 14);
    const int rem   = blk - chunk * (N_ * 14);
    const int n     = rem / 14;
    const int ho2   = rem - n * 14;                 // output row pair: ho = 2*ho2 + hr
    const int c0    = chunk * K1_CCH;
    const int row0  = 4 * ho2 - 1;                  // input row of tile row r=0

    // zero once: ghost cols (0,57) and the ho2==0 ghost top row stay zero forever
    for (int i = tid; i < K1_SC * K1_TR * K1_TW; i += 256) tile[i] = 0.f;

    const int g  = tid >> 6;                        // wave 0..3 -> channel subgroup
    const int p  = tid & 63;
    const int hr = p >> 5;                          // 0/1: which output row of the pair
    const int wo = p & 31;                          // active < 28
    const bool act = wo < WO_;

    float acc[9];
#pragma unroll
    for (int k = 0; k < 9; ++k) acc[k] = 0.f;

    const float* xb = x + ((size_t)n * C_ + c0) * (H_ * W_);

    for (int sub = 0; sub < K1_NSUB; ++sub) {
        __syncthreads();                            // readers of prev sub-chunk done
        // load 16 ch x 5 rows x 14 float4 = 1120 vector loads
        for (int i = tid; i < K1_SC * K1_TR * 14; i += 256) {
            int c    = i / (K1_TR * 14);
            int r2   = i - c * (K1_TR * 14);
            int r    = r2 / 14;
            int kk   = r2 - r * 14;
            int grow = row0 + r;                    // max 4*13-1+4 = 55, only -1 possible OOB
            if (grow >= 0) {
                float4 v = *(const float4*)(xb + ((size_t)(sub * K1_SC + c) * H_ + grow) * W_ + 4 * kk);
                float* d = &tile[(c * K1_TR + r) * K1_TW + 1 + 4 * kk];
                d[0] = v.x; d[1] = v.y; d[2] = v.z; d[3] = v.w;
            }
        }
        __syncthreads();
        if (act) {
#pragma unroll
            for (int cc = 0; cc < K1_SC / 4; ++cc) {
                const int c = cc * 4 + g;
                // window rows: tile rows 2hr..2hr+2; cols 2wo..2wo+2 (tile col = input col + 1)
                const float* tp = &tile[(c * K1_TR + 2 * hr) * K1_TW + 2 * wo]; // even idx -> f2 aligned
                float2 r0 = *(const float2*)(tp);
                float  w2 = tp[2];
                float2 r1 = *(const float2*)(tp + K1_TW);
                float  w5 = tp[K1_TW + 2];
                float2 r2 = *(const float2*)(tp + 2 * K1_TW);
                float  w8 = tp[2 * K1_TW + 2];
                float w0 = r0.x, w1 = r0.y, w3 = r1.x, w4 = r1.y, w6 = r2.x, w7 = r2.y;
                float q = ((w0 + w1) + (w2 + w3)) + ((w4 + w5) + (w6 + w7)) + w8;
                acc[0] += q * w0; acc[1] += q * w1; acc[2] += q * w2;
                acc[3] += q * w3; acc[4] += q * w4; acc[5] += q * w5;
                acc[6] += q * w6; acc[7] += q * w7; acc[8] += q * w8;
            }
        }
    }

    if (act) {
        const int s = hr * 28 + wo;
#pragma unroll
        for (int k = 0; k < 9; ++k) sred[(g * 56 + s) * 9 + k] = acc[k];
    }
    __syncthreads();
    // reduce 4 waves, scale by 1/(9*3), atomicAdd (4 contenders per address)
    for (int i = tid; i < 56 * 9; i += 256) {
        int s = i / 9, k = i - s * 9;
        float t = sred[s * 9 + k]         + sred[(56 + s) * 9 + k]
                + sred[(112 + s) * 9 + k] + sred[(168 + s) * 9 + k];
        int hrr = s / 28, woo = s - hrr * 28;
        int ho  = 2 * ho2 + hrr;
        atomicAdd(&scores[(((size_t)n * HO_ + ho) * WO_ + woo) * 9 + k], t * (1.f / 27.f));
    }
}

// ---- kernel 2: softmax over k=9, in place, LDS-staged coalesced IO ----
__global__ __launch_bounds__(256)
void softmax_kernel(float* __restrict__ scores) {
    __shared__ float sbuf[256 * 9];
    const int tid = threadIdx.x;
    float4* gb = (float4*)(scores + (size_t)blockIdx.x * (256 * 9));   // 9216 B, 16-aligned
    float4* lb = (float4*)sbuf;
    for (int i = tid; i < 576; i += 256) lb[i] = gb[i];
    __syncthreads();
    float v[9];
    float* s = sbuf + tid * 9;                      // stride 9: 2-way bank alias = free
#pragma unroll
    for (int k = 0; k < 9; ++k) v[k] = s[k];
    float m = v[0];
#pragma unroll
    for (int k = 1; k < 9; ++k) m = fmaxf(m, v[k]);
    float d = 0.f;
#pragma unroll
    for (int k = 0; k < 9; ++k) { v[k] = __expf(v[k] - m); d += v[k]; }
    float inv = 1.f / d;
#pragma unroll
    for (int k = 0; k < 9; ++k) s[k] = v[k] * inv;
    __syncthreads();
    for (int i = tid; i < 576; i += 256) gb[i] = lb[i];
}

// ---- kernel 3: merge. one block per (n,c) plane; attn slice staged in LDS ----
constexpr int K3_TW = 58;

__global__ __launch_bounds__(256)
void merge_kernel(const float* __restrict__ x, const float* __restrict__ attn,
                  float* __restrict__ out) {
    __shared__ float tile_raw[4 + K3_TW * K3_TW];   // 13472 B
    __shared__ float attn_s[HO_ * WO_ * 9];         // 28224 B
    float* tile = tile_raw + 4;

    const int tid = threadIdx.x;
    const int blk = blockIdx.x;
    const int n   = blk / C_;                       // consecutive blocks share n -> attn L2-hot
    const int c   = blk - n * C_;

    for (int i = tid; i < 4 + K3_TW * K3_TW; i += 256) tile_raw[i] = 0.f;
    __syncthreads();

    const float* xp = x + ((size_t)n * C_ + c) * (H_ * W_);
    // 56 rows x 14 float4; input row r -> tile row r+1 (ghost top row 0 stays zero)
    for (int i = tid; i < 784; i += 256) {
        int r  = i / 14;
        int kk = i - r * 14;
        float4 v = *(const float4*)(xp + (size_t)r * W_ + 4 * kk);
        float* d = &tile[(r + 1) * K3_TW + 4 * kk];
        d[0] = v.x; d[1] = v.y; d[2] = v.z; d[3] = v.w;
    }
    // stage attn slice for this n: 7056 floats = 1764 float4, coalesced, L2-hot
    const float4* ag = (const float4*)(attn + (size_t)n * (HO_ * WO_ * 9));
    float4* as = (float4*)attn_s;
    for (int i = tid; i < (HO_ * WO_ * 9) / 4; i += 256) as[i] = ag[i];
    __syncthreads();

    float* op = out + ((size_t)n * C_ + c) * (HO_ * WO_);
    for (int p = tid; p < HO_ * WO_; p += 256) {
        int ho = p / WO_, wo = p - ho * WO_;
        const float* a  = &attn_s[p * 9];           // stride 9: 2-way alias = free
        // window rows 2ho-1..2ho+1 -> tile rows 2ho..2ho+2; col -1 hits front pad zero
        const float* tp = &tile[(size_t)(2 * ho) * K3_TW + 2 * wo - 1];
        float y = a[0] * tp[0]           + a[1] * tp[1]             + a[2] * tp[2]
                + a[3] * tp[K3_TW]       + a[4] * tp[K3_TW + 1]     + a[5] * tp[K3_TW + 2]
                + a[6] * tp[2 * K3_TW]   + a[7] * tp[2 * K3_TW + 1] + a[8] * tp[2 * K3_TW + 2];
        op[p] = y;
    }
}

extern "C" void kernel_launch(void* const* d_in, const int* in_sizes, int n_in,
                              void* d_out, int out_size, void* d_ws, size_t ws_size,
                              hipStream_t stream) {
    const float* x   = (const float*)d_in[0];
    float* out       = (float*)d_out;
    float* scores    = (float*)d_ws;               // NPIX*9 floats = 903168 B

    hipMemsetAsync(d_ws, 0, (size_t)NPIX * 9 * sizeof(float), stream);
    scores_kernel<<<dim3(K1_CHUNKS * N_ * 14), dim3(256), 0, stream>>>(x, scores);
    softmax_kernel<<<dim3(NPIX / 256), dim3(256), 0, stream>>>(scores);
    merge_kernel<<<dim3(N_ * C_), dim3(256), 0, stream>>>(x, scores, out);
}

// Round 3
// 576.520 us; speedup vs baseline: 1.0829x; 1.0829x over previous
//
#include <hip/hip_runtime.h>

// AttDownsample: x [32,768,56,56] f32 -> y [32,768,28,28] f32
// v3: single-variable experiment vs v2 — merge restructured to half-plane blocks
// (20.9 KB LDS -> 7 blocks/CU vs v2's 41.7 KB -> 3 blocks/CU) keeping LDS-staged attn.
// scores: v2 structure, LDS store alignment fixed (front-pad, 8B-aligned writes).
// softmax: unchanged. ws: scores/attn [N,Ho,Wo,9] f32 = 903168 B.

constexpr int N_  = 32;
constexpr int C_  = 768;
constexpr int H_  = 56;
constexpr int W_  = 56;
constexpr int HO_ = 28;
constexpr int WO_ = 28;
constexpr int NPIX = N_ * HO_ * WO_;          // 25088

// ---- kernel 1: scores ----
constexpr int K1_CHUNKS = 4;                   // channel chunks (atomic contenders)
constexpr int K1_CCH    = C_ / K1_CHUNKS;      // 192 channels per block
constexpr int K1_SC     = 16;                  // channels per LDS sub-chunk
constexpr int K1_NSUB   = K1_CCH / K1_SC;      // 12
constexpr int K1_TW     = 58;                  // data cols 0..55; 56,57 stay zero (ghost for col -1 of next row)
constexpr int K1_TR     = 5;                   // 5 input rows cover 2 output rows

__global__ __launch_bounds__(256)
void scores_kernel(const float* __restrict__ x, float* __restrict__ scores) {
    __shared__ float tile_raw[4 + K1_SC * K1_TR * K1_TW];   // 18576 B; front pad: raw[3]=0 serves row0 col -1
    __shared__ float sred[4 * 56 * 9];                      // 8064 B
    float* tile = tile_raw + 4;

    const int tid   = threadIdx.x;
    const int blk   = blockIdx.x;
    const int chunk = blk / (N_ * 14);
    const int rem   = blk - chunk * (N_ * 14);
    const int n     = rem / 14;
    const int ho2   = rem - n * 14;                 // output row pair: ho = 2*ho2 + hr
    const int c0    = chunk * K1_CCH;
    const int row0  = 4 * ho2 - 1;                  // input row of tile row r=0

    // zero once: cols 56,57 of every row + front pad + (ho2==0) tile row 0 stay zero forever
    for (int i = tid; i < 4 + K1_SC * K1_TR * K1_TW; i += 256) tile_raw[i] = 0.f;

    const int g  = tid >> 6;                        // wave 0..3 -> channel subgroup
    const int p  = tid & 63;
    const int hr = p >> 5;                          // 0/1: which output row of the pair
    const int wo = p & 31;                          // active < 28
    const bool act = wo < WO_;

    float acc[9];
#pragma unroll
    for (int k = 0; k < 9; ++k) acc[k] = 0.f;

    const float* xb = x + ((size_t)n * C_ + c0) * (H_ * W_);

    for (int sub = 0; sub < K1_NSUB; ++sub) {
        __syncthreads();                            // readers of prev sub-chunk done (covers zero-init on sub 0)
        // load 16 ch x 5 rows x 14 float4 = 1120 vector loads; tile col == input col
        for (int i = tid; i < K1_SC * K1_TR * 14; i += 256) {
            int c    = i / (K1_TR * 14);
            int r2   = i - c * (K1_TR * 14);
            int r    = r2 / 14;
            int kk   = r2 - r * 14;
            int grow = row0 + r;                    // only -1 possible OOB (ho2==0, r==0)
            if (grow >= 0) {
                float4 v = *(const float4*)(xb + ((size_t)(sub * K1_SC + c) * H_ + grow) * W_ + 4 * kk);
                float* d = &tile[(c * K1_TR + r) * K1_TW + 4 * kk];   // 8B-aligned (row base even, TW=58)
                d[0] = v.x; d[1] = v.y; d[2] = v.z; d[3] = v.w;
            }
        }
        __syncthreads();
        if (act) {
#pragma unroll
            for (int cc = 0; cc < K1_SC / 4; ++cc) {
                const int c = cc * 4 + g;
                // window rows: tile rows 2hr..2hr+2; cols 2wo-1..2wo+1 (wo=0 col -1 -> zero slot)
                const float* tp = &tile[(c * K1_TR + 2 * hr) * K1_TW + 2 * wo - 1];
                float w0 = tp[0],          w1 = tp[1],             w2 = tp[2];
                float w3 = tp[K1_TW],      w4 = tp[K1_TW + 1],     w5 = tp[K1_TW + 2];
                float w6 = tp[2 * K1_TW],  w7 = tp[2 * K1_TW + 1], w8 = tp[2 * K1_TW + 2];
                float q = ((w0 + w1) + (w2 + w3)) + ((w4 + w5) + (w6 + w7)) + w8;  // sum; /27 at end
                acc[0] += q * w0; acc[1] += q * w1; acc[2] += q * w2;
                acc[3] += q * w3; acc[4] += q * w4; acc[5] += q * w5;
                acc[6] += q * w6; acc[7] += q * w7; acc[8] += q * w8;
            }
        }
    }

    if (act) {
        const int s = hr * 28 + wo;
#pragma unroll
        for (int k = 0; k < 9; ++k) sred[(g * 56 + s) * 9 + k] = acc[k];
    }
    __syncthreads();
    // reduce 4 waves, scale by 1/(9*3), atomicAdd (4 contenders per address)
    for (int i = tid; i < 56 * 9; i += 256) {
        int s = i / 9, k = i - s * 9;
        float t = sred[s * 9 + k]         + sred[(56 + s) * 9 + k]
                + sred[(112 + s) * 9 + k] + sred[(168 + s) * 9 + k];
        int hrr = s / 28, woo = s - hrr * 28;
        int ho  = 2 * ho2 + hrr;
        atomicAdd(&scores[(((size_t)n * HO_ + ho) * WO_ + woo) * 9 + k], t * (1.f / 27.f));
    }
}

// ---- kernel 2: softmax over k=9, in place, LDS-staged coalesced IO ----
__global__ __launch_bounds__(256)
void softmax_kernel(float* __restrict__ scores) {
    __shared__ float sbuf[256 * 9];
    const int tid = threadIdx.x;
    float4* gb = (float4*)(scores + (size_t)blockIdx.x * (256 * 9));   // 9216 B, 16-aligned
    float4* lb = (float4*)sbuf;
    for (int i = tid; i < 576; i += 256) lb[i] = gb[i];
    __syncthreads();
    float v[9];
    float* s = sbuf + tid * 9;                      // stride 9: all 32 banks, 2-way = free
#pragma unroll
    for (int k = 0; k < 9; ++k) v[k] = s[k];
    float m = v[0];
#pragma unroll
    for (int k = 1; k < 9; ++k) m = fmaxf(m, v[k]);
    float d = 0.f;
#pragma unroll
    for (int k = 0; k < 9; ++k) { v[k] = __expf(v[k] - m); d += v[k]; }
    float inv = 1.f / d;
#pragma unroll
    for (int k = 0; k < 9; ++k) s[k] = v[k] * inv;
    __syncthreads();
    for (int i = tid; i < 576; i += 256) gb[i] = lb[i];
}

// ---- kernel 3: merge. one block per (n, c, half-plane); attn half-slice in LDS ----
constexpr int K3_ROWS = 29;                    // input rows r0..r0+28, r0 = 28*h - 1
constexpr int K3_TW   = 58;                    // data cols 0..55; 56,57 zero (ghost for col -1)

__global__ __launch_bounds__(256)
void merge_kernel(const float* __restrict__ x, const float* __restrict__ attn,
                  float* __restrict__ out) {
    __shared__ float tile_raw[4 + K3_ROWS * K3_TW];  // 6744 B
    __shared__ float attn_s[14 * WO_ * 9];           // 14112 B  -> total 20.9 KB, 7 blocks/CU
    float* tile = tile_raw + 4;

    const int tid = threadIdx.x;
    const int blk = blockIdx.x;
    const int n   = blk / (C_ * 2);                  // consecutive blocks share n -> attn L2-hot
    const int rem = blk - n * (C_ * 2);
    const int c   = rem >> 1;
    const int h   = rem & 1;                         // half-plane: ho in [14h, 14h+14)
    const int r0  = 28 * h - 1;                      // input row of tile row 0

    for (int i = tid; i < 4 + K3_ROWS * K3_TW; i += 256) tile_raw[i] = 0.f;
    __syncthreads();

    const float* xp = x + ((size_t)n * C_ + c) * (H_ * W_);
    // 29 rows x 14 float4; h=0 skips tr=0 (row -1 stays zero)
    for (int i = tid; i < K3_ROWS * 14; i += 256) {
        int tr = i / 14;
        int kk = i - tr * 14;
        int grow = r0 + tr;                          // h=1: max 55, in range
        if (grow >= 0) {
            float4 v = *(const float4*)(xp + (size_t)grow * W_ + 4 * kk);
            float* d = &tile[tr * K3_TW + 4 * kk];
            d[0] = v.x; d[1] = v.y; d[2] = v.z; d[3] = v.w;
        }
    }
    // stage attn half-slice: 3528 floats = 882 float4, coalesced, L2-hot
    const float4* ag = (const float4*)(attn + ((size_t)n * 784 + h * 392) * 9);
    float4* as = (float4*)attn_s;
    for (int i = tid; i < 882; i += 256) as[i] = ag[i];
    __syncthreads();

    float* op = out + ((size_t)n * C_ + c) * (HO_ * WO_) + h * 392;
    for (int p = tid; p < 392; p += 256) {
        int ho_l = p / WO_, wo = p - ho_l * WO_;
        const float* a  = &attn_s[p * 9];            // stride 9: all 32 banks, 2-way = free
        // window rows 2ho-1..2ho+1 -> tile rows 2ho_l..2ho_l+2; col -1 hits zero slot
        const float* tp = &tile[(size_t)(2 * ho_l) * K3_TW + 2 * wo - 1];
        float y = a[0] * tp[0]           + a[1] * tp[1]             + a[2] * tp[2]
                + a[3] * tp[K3_TW]       + a[4] * tp[K3_TW + 1]     + a[5] * tp[K3_TW + 2]
                + a[6] * tp[2 * K3_TW]   + a[7] * tp[2 * K3_TW + 1] + a[8] * tp[2 * K3_TW + 2];
        op[p] = y;
    }
}

extern "C" void kernel_launch(void* const* d_in, const int* in_sizes, int n_in,
                              void* d_out, int out_size, void* d_ws, size_t ws_size,
                              hipStream_t stream) {
    const float* x   = (const float*)d_in[0];
    float* out       = (float*)d_out;
    float* scores    = (float*)d_ws;               // NPIX*9 floats = 903168 B

    hipMemsetAsync(d_ws, 0, (size_t)NPIX * 9 * sizeof(float), stream);
    scores_kernel<<<dim3(K1_CHUNKS * N_ * 14), dim3(256), 0, stream>>>(x, scores);
    softmax_kernel<<<dim3(NPIX / 256), dim3(256), 0, stream>>>(scores);
    merge_kernel<<<dim3(N_ * C_ * 2), dim3(256), 0, stream>>>(x, scores, out);
}